// Round 5
// baseline (309.164 us; speedup 1.0000x reference)
//
#include <hip/hip_runtime.h>

// Workspace layout (float offsets). H makes total ~18 MB of ws.
#define WS_SC1    0         // [26][5][32][32] pooled conv1
#define WS_FEAT   133120    // [26][1960]      pooled conv2 (flattened)
#define WS_FC1P   184080    // [26][500]       fc1 class-part + bias
#define WS_FC2P   197080    // [125][64][4]    fc2 weights packed float4 by (j4,e)
#define WS_AFLAT  229080    // [64][4]         A_B + A_C
#define WS_WX     229336    // [500][2]        fc1_w columns 1960,1961
#define WS_H      262144    // [8192][500]     per-sample hidden h (16.4 MB)

// ---------------------------------------------------------------------------
// K1a: conv1 + relu + pool2. blocks 0..519: (class, oc, row-group); one pooled
// output per thread, weights in SGPRs, image via L1/L2.
// blocks 520,521: prep (fc2 float4 pack; Aflat; Wx).
// ---------------------------------------------------------------------------
__global__ __launch_bounds__(256) void k_conv1(
    const float* __restrict__ images, const float* __restrict__ c1w,
    const float* __restrict__ c1b, const float* __restrict__ fc2w,
    const float* __restrict__ fc1w, const float* __restrict__ A_B,
    const float* __restrict__ A_C, float* __restrict__ ws)
{
    const int b = blockIdx.x, t = threadIdx.x;
    if (b >= 520) {
        if (b == 520) {
            float* P = ws + WS_FC2P;
            for (int i = t; i < 8000; i += 256) {   // i = j4*64 + e
                int j4 = i >> 6, e = i & 63;
                float4 v;
                v.x = fc2w[e * 500 + 4 * j4 + 0];
                v.y = fc2w[e * 500 + 4 * j4 + 1];
                v.z = fc2w[e * 500 + 4 * j4 + 2];
                v.w = fc2w[e * 500 + 4 * j4 + 3];
                *(float4*)&P[i * 4] = v;
            }
        } else {
            float* Af = ws + WS_AFLAT;
            if (t < 256) Af[t] = A_B[t] + A_C[t];
            float* Wx = ws + WS_WX;
            for (int i = t; i < 1000; i += 256) {
                int j = i >> 1, k = i & 1;
                Wx[i] = fc1w[j * 1962 + 1960 + k];
            }
        }
        return;
    }

    const int c = b / 20, r = b - c * 20;
    const int oc = r >> 2, g = r & 3;
    const int py = g * 8 + (t >> 5), px = t & 31;

    float wr[25];
#pragma unroll
    for (int i = 0; i < 25; ++i) wr[i] = c1w[oc * 25 + i];
    const float bias = c1b[oc];

    const float* im = images + c * 4624 + (2 * py) * 68 + 2 * px;
    float ir[6][6];
#pragma unroll
    for (int a = 0; a < 6; ++a)
#pragma unroll
        for (int q = 0; q < 3; ++q) {
            float2 v = *(const float2*)&im[a * 68 + 2 * q];
            ir[a][2 * q] = v.x; ir[a][2 * q + 1] = v.y;
        }

    float a00 = bias, a01 = bias, a10 = bias, a11 = bias;
#pragma unroll
    for (int ky = 0; ky < 5; ++ky)
#pragma unroll
        for (int kx = 0; kx < 5; ++kx) {
            float w = wr[ky * 5 + kx];
            a00 += w * ir[ky][kx];     a01 += w * ir[ky][kx + 1];
            a10 += w * ir[ky + 1][kx]; a11 += w * ir[ky + 1][kx + 1];
        }
    float v = fmaxf(fmaxf(fmaxf(a00, a01), fmaxf(a10, a11)), 0.f);
    ws[WS_SC1 + ((c * 5 + oc) * 32 + py) * 32 + px] = v;
}

// ---------------------------------------------------------------------------
// K1b: conv2 + relu + pool2. 260 blocks = (class, oc); threads 0..195 one
// pooled output each; weights via LDS broadcast, inputs via L1/L2.
// ---------------------------------------------------------------------------
__global__ __launch_bounds__(256) void k_conv2(
    const float* __restrict__ c2w, const float* __restrict__ c2b,
    float* __restrict__ ws)
{
    const int b = blockIdx.x, t = threadIdx.x;
    const int c = b / 10, oc = b - c * 10;

    __shared__ float sw[125];
    if (t < 125) sw[t] = c2w[oc * 125 + t];
    __syncthreads();
    if (t >= 196) return;

    const int py = t / 14, px = t - py * 14;
    const float bias = c2b[oc];
    float a00 = bias, a01 = bias, a10 = bias, a11 = bias;

    const float* base = ws + WS_SC1 + c * 5120 + (2 * py) * 32 + 2 * px;
#pragma unroll
    for (int ic = 0; ic < 5; ++ic) {
        const float* s1 = base + ic * 1024;
        float ir[6][6];
#pragma unroll
        for (int a = 0; a < 6; ++a)
#pragma unroll
            for (int q = 0; q < 3; ++q) {
                float2 v = *(const float2*)&s1[a * 32 + 2 * q];
                ir[a][2 * q] = v.x; ir[a][2 * q + 1] = v.y;
            }
#pragma unroll
        for (int ky = 0; ky < 5; ++ky)
#pragma unroll
            for (int kx = 0; kx < 5; ++kx) {
                float w = sw[ic * 25 + ky * 5 + kx];
                a00 += w * ir[ky][kx];     a01 += w * ir[ky][kx + 1];
                a10 += w * ir[ky + 1][kx]; a11 += w * ir[ky + 1][kx + 1];
            }
    }
    float v = fmaxf(fmaxf(fmaxf(a00, a01), fmaxf(a10, a11)), 0.f);
    ws[WS_FEAT + c * 1960 + oc * 196 + py * 14 + px] = v;
}

// ---------------------------------------------------------------------------
// K2: fc1. 1638 blocks = (class c, j-group of 8); 2 full j-dots per wave.
// ---------------------------------------------------------------------------
__global__ __launch_bounds__(256) void k_fc1(
    const float* __restrict__ fc1w, const float* __restrict__ fc1b,
    float* __restrict__ ws)
{
    const int lane = threadIdx.x & 63, w = threadIdx.x >> 6;
    const int c = blockIdx.x / 63, jg = blockIdx.x - c * 63;
    const int j0 = jg * 8 + 2 * w;
    if (j0 >= 500) return;
    const int j1 = j0 + 1;

    const float* f  = ws + WS_FEAT + c * 1960;
    const float* w0 = fc1w + j0 * 1962;
    const float* w1 = fc1w + j1 * 1962;

    float acc0 = 0.f, acc1 = 0.f;
#pragma unroll
    for (int i = 0; i < 30; ++i) {
        int k = lane + 64 * i;
        float fv = f[k];
        acc0 += w0[k] * fv;
        acc1 += w1[k] * fv;
    }
    {
        int k = lane + 1920;
        if (k < 1960) {
            float fv = f[k];
            acc0 += w0[k] * fv;
            acc1 += w1[k] * fv;
        }
    }
#pragma unroll
    for (int off = 32; off >= 1; off >>= 1) {
        acc0 += __shfl_xor(acc0, off);
        acc1 += __shfl_xor(acc1, off);
    }
    if (lane == 0) {
        ws[WS_FC1P + c * 500 + j0] = acc0 + fc1b[j0];
        ws[WS_FC1P + c * 500 + j1] = acc1 + fc1b[j1];
    }
}

// ---------------------------------------------------------------------------
// K3a: materialize H[8192][500] = relu(fc1p[cls] + x.Wx). 1024 blocks,
// 8 samples each; coalesced float2 stores; fc1p/Wx L2/L1-hot.
// ---------------------------------------------------------------------------
__global__ __launch_bounds__(256) void k_h(
    const float* __restrict__ x, const int* __restrict__ cls,
    float* __restrict__ ws)
{
    const int t = threadIdx.x;
    const int b0 = blockIdx.x * 8;
    const float* fc1p = ws + WS_FC1P;
    const float* Wx   = ws + WS_WX;
    float* H = ws + WS_H;

#pragma unroll
    for (int s = 0; s < 8; ++s) {
        const int b = b0 + s;
        const int c = cls[b];                 // uniform -> scalar load
        const float x0 = x[2 * b], x1 = x[2 * b + 1];
        const float* fr = fc1p + c * 500;
        float* hr = H + (size_t)b * 500;
        for (int j2 = t; j2 < 250; j2 += 256) {
            float2 f  = *(const float2*)&fr[2 * j2];
            float4 wx = *(const float4*)&Wx[4 * j2];
            float h0 = fmaxf(f.x + x0 * wx.x + x1 * wx.y, 0.f);
            float h1 = fmaxf(f.y + x0 * wx.z + x1 * wx.w, 0.f);
            *(float2*)&hr[2 * j2] = make_float2(h0, h1);
        }
    }
}

// ---------------------------------------------------------------------------
// K3b: logits + softmax + expert combine. 512 blocks x 16 samples.
// lane = expert e; wave pu owns a j4-chunk (32/32/32/29 of 125).
// fc2 weights: 128 VGPRs/lane (coalesced float4). h: uniform-address float4
// loads (s_load_dwordx4) consumed as the SGPR operand of v_fmac — no LDS in
// the hot loop. Partials -> 16KB LDS -> per-wave softmax + A-combine.
// ---------------------------------------------------------------------------
__global__ __launch_bounds__(256) void k_logits(
    const float* __restrict__ x, const float* __restrict__ fc2b,
    const float* __restrict__ x_tar, const float* __restrict__ ws,
    float* __restrict__ out)
{
    __shared__ float sred[4096];   // [chunk q][sample s][expert e]
    const int t = threadIdx.x;
    const int e = t & 63;
    const int pu = __builtin_amdgcn_readfirstlane(t >> 6);  // wave-uniform
    const int b0 = blockIdx.x * 16;
    const float* H    = ws + WS_H;
    const float* fc2P = ws + WS_FC2P;
    const float* Af   = ws + WS_AFLAT;

    const int jbeg4 = pu * 32;
    const int jcnt4 = (pu == 3) ? 29 : 32;

    float4 w[32];
    for (int i = 0; i < jcnt4; ++i)
        w[i] = *(const float4*)&fc2P[((jbeg4 + i) * 64 + e) * 4];

    for (int s = 0; s < 16; ++s) {
        const float* hrow = H + (size_t)(b0 + s) * 500 + jbeg4 * 4;  // uniform
        float a = 0.f;
        for (int i = 0; i < jcnt4; ++i) {
            float4 h4 = *(const float4*)&hrow[4 * i];   // s_load_dwordx4
            a += h4.x * w[i].x + h4.y * w[i].y + h4.z * w[i].z + h4.w * w[i].w;
        }
        sred[(pu * 16 + s) * 64 + e] = a;
    }
    __syncthreads();

    const float xt0 = x_tar[0], xt1 = x_tar[1];
    const float be = fc2b[e];
    const float4 a4 = *(const float4*)&Af[4 * e];
#pragma unroll
    for (int k = 0; k < 4; ++k) {
        const int s = pu * 4 + k;
        float logit = be + sred[s * 64 + e] + sred[(16 + s) * 64 + e]
                    + sred[(32 + s) * 64 + e] + sred[(48 + s) * 64 + e];
        float m = logit;
#pragma unroll
        for (int off = 32; off >= 1; off >>= 1) m = fmaxf(m, __shfl_xor(m, off));
        float ex = __expf(logit - m);
        float sum = ex;
        float m0 = ex * a4.x, m1 = ex * a4.y, m2 = ex * a4.z, m3 = ex * a4.w;
#pragma unroll
        for (int off = 32; off >= 1; off >>= 1) {
            sum += __shfl_xor(sum, off);
            m0 += __shfl_xor(m0, off);
            m1 += __shfl_xor(m1, off);
            m2 += __shfl_xor(m2, off);
            m3 += __shfl_xor(m3, off);
        }
        if (e == 0) {
            const int b = b0 + s;
            float d0 = xt0 - x[2 * b], d1 = xt1 - x[2 * b + 1];
            float inv = 1.f / sum;
            out[2 * b]     = (m0 * d0 + m1 * d1) * inv;
            out[2 * b + 1] = (m2 * d0 + m3 * d1) * inv;
        }
    }
}

extern "C" void kernel_launch(void* const* d_in, const int* in_sizes, int n_in,
                              void* d_out, int out_size, void* d_ws, size_t ws_size,
                              hipStream_t stream) {
    const float* x      = (const float*)d_in[0];
    const int*   cls    = (const int*)  d_in[1];
    const float* images = (const float*)d_in[2];
    const float* c1w    = (const float*)d_in[3];
    const float* c1b    = (const float*)d_in[4];
    const float* c2w    = (const float*)d_in[5];
    const float* c2b    = (const float*)d_in[6];
    const float* fc1w   = (const float*)d_in[7];
    const float* fc1b   = (const float*)d_in[8];
    const float* fc2w   = (const float*)d_in[9];
    const float* fc2b   = (const float*)d_in[10];
    const float* A_B    = (const float*)d_in[11];
    const float* A_C    = (const float*)d_in[12];
    const float* x_tar  = (const float*)d_in[13];
    float* out = (float*)d_out;
    float* ws  = (float*)d_ws;

    k_conv1 <<<522, 256, 0, stream>>>(images, c1w, c1b, fc2w, fc1w, A_B, A_C, ws);
    k_conv2 <<<260, 256, 0, stream>>>(c2w, c2b, ws);
    k_fc1   <<<1638, 256, 0, stream>>>(fc1w, fc1b, ws);
    k_h     <<<1024, 256, 0, stream>>>(x, cls, ws);
    k_logits<<<512, 256, 0, stream>>>(x, fc2b, x_tar, ws, out);
}

// Round 6
// 175.548 us; speedup vs baseline: 1.7611x; 1.7611x over previous
//
#include <hip/hip_runtime.h>

// Workspace layout (float offsets). H makes total ~17 MB of ws.
#define WS_SC1    0         // [26][5][32][32] pooled conv1
#define WS_FEAT   133120    // [26][1960]      pooled conv2 (flattened)
#define WS_FC1P   184080    // [26][500]       fc1 class-part + bias
#define WS_FC2P   197080    // [128][64][4]    fc2 weights packed float4 by (j4,e), j4>=125 zero
#define WS_AFLAT  229848    // [64][4]         A_B + A_C
#define WS_WX     230104    // [500][2]        fc1_w columns 1960,1961
#define WS_H      262144    // [8192][512]     per-sample hidden h (padded rows)

// ---------------------------------------------------------------------------
// K1a: conv1 + relu + pool2. blocks 0..519: (class, oc, row-group); one pooled
// output per thread, weights in SGPRs, image via L1/L2.
// blocks 520,521: prep (fc2 float4 pack incl. zero pad; Aflat; Wx).
// ---------------------------------------------------------------------------
__global__ __launch_bounds__(256) void k_conv1(
    const float* __restrict__ images, const float* __restrict__ c1w,
    const float* __restrict__ c1b, const float* __restrict__ fc2w,
    const float* __restrict__ fc1w, const float* __restrict__ A_B,
    const float* __restrict__ A_C, float* __restrict__ ws)
{
    const int b = blockIdx.x, t = threadIdx.x;
    if (b >= 520) {
        if (b == 520) {
            float* P = ws + WS_FC2P;
            for (int i = t; i < 8192; i += 256) {   // i = j4*64 + e, j4 < 128
                int j4 = i >> 6, e = i & 63;
                float4 v = make_float4(0.f, 0.f, 0.f, 0.f);
                if (j4 < 125) {
                    v.x = fc2w[e * 500 + 4 * j4 + 0];
                    v.y = fc2w[e * 500 + 4 * j4 + 1];
                    v.z = fc2w[e * 500 + 4 * j4 + 2];
                    v.w = fc2w[e * 500 + 4 * j4 + 3];
                }
                *(float4*)&P[i * 4] = v;
            }
        } else {
            float* Af = ws + WS_AFLAT;
            if (t < 256) Af[t] = A_B[t] + A_C[t];
            float* Wx = ws + WS_WX;
            for (int i = t; i < 1000; i += 256) {
                int j = i >> 1, k = i & 1;
                Wx[i] = fc1w[j * 1962 + 1960 + k];
            }
        }
        return;
    }

    const int c = b / 20, r = b - c * 20;
    const int oc = r >> 2, g = r & 3;
    const int py = g * 8 + (t >> 5), px = t & 31;

    float wr[25];
#pragma unroll
    for (int i = 0; i < 25; ++i) wr[i] = c1w[oc * 25 + i];
    const float bias = c1b[oc];

    const float* im = images + c * 4624 + (2 * py) * 68 + 2 * px;
    float ir[6][6];
#pragma unroll
    for (int a = 0; a < 6; ++a)
#pragma unroll
        for (int q = 0; q < 3; ++q) {
            float2 v = *(const float2*)&im[a * 68 + 2 * q];
            ir[a][2 * q] = v.x; ir[a][2 * q + 1] = v.y;
        }

    float a00 = bias, a01 = bias, a10 = bias, a11 = bias;
#pragma unroll
    for (int ky = 0; ky < 5; ++ky)
#pragma unroll
        for (int kx = 0; kx < 5; ++kx) {
            float w = wr[ky * 5 + kx];
            a00 += w * ir[ky][kx];     a01 += w * ir[ky][kx + 1];
            a10 += w * ir[ky + 1][kx]; a11 += w * ir[ky + 1][kx + 1];
        }
    float v = fmaxf(fmaxf(fmaxf(a00, a01), fmaxf(a10, a11)), 0.f);
    ws[WS_SC1 + ((c * 5 + oc) * 32 + py) * 32 + px] = v;
}

// ---------------------------------------------------------------------------
// K1b: conv2 + relu + pool2. 260 blocks = (class, oc); threads 0..195 one
// pooled output each; weights via LDS broadcast, inputs via L1/L2.
// ---------------------------------------------------------------------------
__global__ __launch_bounds__(256) void k_conv2(
    const float* __restrict__ c2w, const float* __restrict__ c2b,
    float* __restrict__ ws)
{
    const int b = blockIdx.x, t = threadIdx.x;
    const int c = b / 10, oc = b - c * 10;

    __shared__ float sw[125];
    if (t < 125) sw[t] = c2w[oc * 125 + t];
    __syncthreads();
    if (t >= 196) return;

    const int py = t / 14, px = t - py * 14;
    const float bias = c2b[oc];
    float a00 = bias, a01 = bias, a10 = bias, a11 = bias;

    const float* base = ws + WS_SC1 + c * 5120 + (2 * py) * 32 + 2 * px;
#pragma unroll
    for (int ic = 0; ic < 5; ++ic) {
        const float* s1 = base + ic * 1024;
        float ir[6][6];
#pragma unroll
        for (int a = 0; a < 6; ++a)
#pragma unroll
            for (int q = 0; q < 3; ++q) {
                float2 v = *(const float2*)&s1[a * 32 + 2 * q];
                ir[a][2 * q] = v.x; ir[a][2 * q + 1] = v.y;
            }
#pragma unroll
        for (int ky = 0; ky < 5; ++ky)
#pragma unroll
            for (int kx = 0; kx < 5; ++kx) {
                float w = sw[ic * 25 + ky * 5 + kx];
                a00 += w * ir[ky][kx];     a01 += w * ir[ky][kx + 1];
                a10 += w * ir[ky + 1][kx]; a11 += w * ir[ky + 1][kx + 1];
            }
    }
    float v = fmaxf(fmaxf(fmaxf(a00, a01), fmaxf(a10, a11)), 0.f);
    ws[WS_FEAT + c * 1960 + oc * 196 + py * 14 + px] = v;
}

// ---------------------------------------------------------------------------
// K2: fc1. 1638 blocks = (class c, j-group of 8); 2 full j-dots per wave.
// ---------------------------------------------------------------------------
__global__ __launch_bounds__(256) void k_fc1(
    const float* __restrict__ fc1w, const float* __restrict__ fc1b,
    float* __restrict__ ws)
{
    const int lane = threadIdx.x & 63, w = threadIdx.x >> 6;
    const int c = blockIdx.x / 63, jg = blockIdx.x - c * 63;
    const int j0 = jg * 8 + 2 * w;
    if (j0 >= 500) return;
    const int j1 = j0 + 1;

    const float* f  = ws + WS_FEAT + c * 1960;
    const float* w0 = fc1w + j0 * 1962;
    const float* w1 = fc1w + j1 * 1962;

    float acc0 = 0.f, acc1 = 0.f;
#pragma unroll
    for (int i = 0; i < 30; ++i) {
        int k = lane + 64 * i;
        float fv = f[k];
        acc0 += w0[k] * fv;
        acc1 += w1[k] * fv;
    }
    {
        int k = lane + 1920;
        if (k < 1960) {
            float fv = f[k];
            acc0 += w0[k] * fv;
            acc1 += w1[k] * fv;
        }
    }
#pragma unroll
    for (int off = 32; off >= 1; off >>= 1) {
        acc0 += __shfl_xor(acc0, off);
        acc1 += __shfl_xor(acc1, off);
    }
    if (lane == 0) {
        ws[WS_FC1P + c * 500 + j0] = acc0 + fc1b[j0];
        ws[WS_FC1P + c * 500 + j1] = acc1 + fc1b[j1];
    }
}

// ---------------------------------------------------------------------------
// K3a: materialize H[8192][512] = relu(fc1p[cls] + x.Wx), tail zeroed.
// 1024 blocks, 8 samples each; coalesced float2 stores.
// ---------------------------------------------------------------------------
__global__ __launch_bounds__(256) void k_h(
    const float* __restrict__ x, const int* __restrict__ cls,
    float* __restrict__ ws)
{
    const int t = threadIdx.x;
    const int b0 = blockIdx.x * 8;
    const float* fc1p = ws + WS_FC1P;
    const float* Wx   = ws + WS_WX;
    float* H = ws + WS_H;

#pragma unroll
    for (int s = 0; s < 8; ++s) {
        const int b = b0 + s;
        const int c = cls[b];
        const float x0 = x[2 * b], x1 = x[2 * b + 1];
        const float* fr = fc1p + c * 500;
        float* hr = H + (size_t)b * 512;
        for (int j2 = t; j2 < 250; j2 += 256) {
            float2 f  = *(const float2*)&fr[2 * j2];
            float4 wx = *(const float4*)&Wx[4 * j2];
            float h0 = fmaxf(f.x + x0 * wx.x + x1 * wx.y, 0.f);
            float h1 = fmaxf(f.y + x0 * wx.z + x1 * wx.w, 0.f);
            *(float2*)&hr[2 * j2] = make_float2(h0, h1);
        }
        if (t < 6) *(float2*)&hr[500 + 2 * t] = make_float2(0.f, 0.f);
    }
}

// ---------------------------------------------------------------------------
// K3b: logits + softmax + expert combine. 512 blocks x 16 samples.
// lane = expert e; wave pu owns a COMPILE-TIME 32-chunk of j4 (padded to 128).
// fc2 weights: 128 VGPRs/lane (register-resident: constant trip count + full
// unroll — R5's runtime bound spilled to scratch, 527 MB FETCH). h rows:
// wave-uniform address -> scalar loads; no LDS in hot loop.
// ---------------------------------------------------------------------------
__global__ __launch_bounds__(256) void k_logits(
    const float* __restrict__ x, const float* __restrict__ fc2b,
    const float* __restrict__ x_tar, const float* __restrict__ ws,
    float* __restrict__ out)
{
    __shared__ float sred[4096];   // [chunk q][sample s][expert e]
    const int t = threadIdx.x;
    const int e = t & 63;
    const int pu = __builtin_amdgcn_readfirstlane(t >> 6);  // wave-uniform
    const int b0 = blockIdx.x * 16;
    const float* H    = ws + WS_H;
    const float* fc2P = ws + WS_FC2P;
    const float* Af   = ws + WS_AFLAT;

    const int jbeg4 = pu * 32;

    float4 w[32];
#pragma unroll
    for (int i = 0; i < 32; ++i)
        w[i] = *(const float4*)&fc2P[((jbeg4 + i) * 64 + e) * 4];

    for (int s = 0; s < 16; ++s) {
        const float* hrow = H + (size_t)(b0 + s) * 512 + jbeg4 * 4;  // uniform
        float a = 0.f;
#pragma unroll
        for (int i = 0; i < 32; ++i) {
            float4 h4 = *(const float4*)&hrow[4 * i];
            a += h4.x * w[i].x + h4.y * w[i].y + h4.z * w[i].z + h4.w * w[i].w;
        }
        sred[(pu * 16 + s) * 64 + e] = a;
    }
    __syncthreads();

    const float xt0 = x_tar[0], xt1 = x_tar[1];
    const float be = fc2b[e];
    const float4 a4 = *(const float4*)&Af[4 * e];
#pragma unroll
    for (int k = 0; k < 4; ++k) {
        const int s = pu * 4 + k;
        float logit = be + sred[s * 64 + e] + sred[(16 + s) * 64 + e]
                    + sred[(32 + s) * 64 + e] + sred[(48 + s) * 64 + e];
        float m = logit;
#pragma unroll
        for (int off = 32; off >= 1; off >>= 1) m = fmaxf(m, __shfl_xor(m, off));
        float ex = __expf(logit - m);
        float sum = ex;
        float m0 = ex * a4.x, m1 = ex * a4.y, m2 = ex * a4.z, m3 = ex * a4.w;
#pragma unroll
        for (int off = 32; off >= 1; off >>= 1) {
            sum += __shfl_xor(sum, off);
            m0 += __shfl_xor(m0, off);
            m1 += __shfl_xor(m1, off);
            m2 += __shfl_xor(m2, off);
            m3 += __shfl_xor(m3, off);
        }
        if (e == 0) {
            const int b = b0 + s;
            float d0 = xt0 - x[2 * b], d1 = xt1 - x[2 * b + 1];
            float inv = 1.f / sum;
            out[2 * b]     = (m0 * d0 + m1 * d1) * inv;
            out[2 * b + 1] = (m2 * d0 + m3 * d1) * inv;
        }
    }
}

extern "C" void kernel_launch(void* const* d_in, const int* in_sizes, int n_in,
                              void* d_out, int out_size, void* d_ws, size_t ws_size,
                              hipStream_t stream) {
    const float* x      = (const float*)d_in[0];
    const int*   cls    = (const int*)  d_in[1];
    const float* images = (const float*)d_in[2];
    const float* c1w    = (const float*)d_in[3];
    const float* c1b    = (const float*)d_in[4];
    const float* c2w    = (const float*)d_in[5];
    const float* c2b    = (const float*)d_in[6];
    const float* fc1w   = (const float*)d_in[7];
    const float* fc1b   = (const float*)d_in[8];
    const float* fc2w   = (const float*)d_in[9];
    const float* fc2b   = (const float*)d_in[10];
    const float* A_B    = (const float*)d_in[11];
    const float* A_C    = (const float*)d_in[12];
    const float* x_tar  = (const float*)d_in[13];
    float* out = (float*)d_out;
    float* ws  = (float*)d_ws;

    k_conv1 <<<522, 256, 0, stream>>>(images, c1w, c1b, fc2w, fc1w, A_B, A_C, ws);
    k_conv2 <<<260, 256, 0, stream>>>(c2w, c2b, ws);
    k_fc1   <<<1638, 256, 0, stream>>>(fc1w, fc1b, ws);
    k_h     <<<1024, 256, 0, stream>>>(x, cls, ws);
    k_logits<<<512, 256, 0, stream>>>(x, fc2b, x_tar, ws, out);
}

// Round 7
// 146.319 us; speedup vs baseline: 2.1129x; 1.1998x over previous
//
#include <hip/hip_runtime.h>

// Workspace layout (float offsets), ~930 KB of ws used.
#define WS_SC1    0         // [26][5][32][32] pooled conv1
#define WS_FEAT   133120    // [26][1960]      pooled conv2 (flattened)
#define WS_FC1P   184080    // [26][500]       fc1 class-part + bias
#define WS_W2     197080    // [500][64]       fc2 weights, k-major
#define WS_AFLAT  229848    // [64][4]         A_B + A_C
#define WS_WX     230104    // [500][2]        fc1_w columns 1960,1961

// ---------------------------------------------------------------------------
// K1a: conv1 + relu + pool2. blocks 0..519: (class, oc, row-group); one pooled
// output per thread, weights in SGPRs, image via L1/L2.
// blocks 520,521: prep (W2 k-major pack; Aflat; Wx).
// ---------------------------------------------------------------------------
__global__ __launch_bounds__(256) void k_conv1(
    const float* __restrict__ images, const float* __restrict__ c1w,
    const float* __restrict__ c1b, const float* __restrict__ fc2w,
    const float* __restrict__ fc1w, const float* __restrict__ A_B,
    const float* __restrict__ A_C, float* __restrict__ ws)
{
    const int b = blockIdx.x, t = threadIdx.x;
    if (b >= 520) {
        if (b == 520) {
            float* W2 = ws + WS_W2;
            for (int i = t; i < 32000; i += 256) {   // i = k*64 + e
                int k = i >> 6, e = i & 63;
                W2[i] = fc2w[e * 500 + k];
            }
        } else {
            float* Af = ws + WS_AFLAT;
            if (t < 256) Af[t] = A_B[t] + A_C[t];
            float* Wx = ws + WS_WX;
            for (int i = t; i < 1000; i += 256) {
                int j = i >> 1, k = i & 1;
                Wx[i] = fc1w[j * 1962 + 1960 + k];
            }
        }
        return;
    }

    const int c = b / 20, r = b - c * 20;
    const int oc = r >> 2, g = r & 3;
    const int py = g * 8 + (t >> 5), px = t & 31;

    float wr[25];
#pragma unroll
    for (int i = 0; i < 25; ++i) wr[i] = c1w[oc * 25 + i];
    const float bias = c1b[oc];

    const float* im = images + c * 4624 + (2 * py) * 68 + 2 * px;
    float ir[6][6];
#pragma unroll
    for (int a = 0; a < 6; ++a)
#pragma unroll
        for (int q = 0; q < 3; ++q) {
            float2 v = *(const float2*)&im[a * 68 + 2 * q];
            ir[a][2 * q] = v.x; ir[a][2 * q + 1] = v.y;
        }

    float a00 = bias, a01 = bias, a10 = bias, a11 = bias;
#pragma unroll
    for (int ky = 0; ky < 5; ++ky)
#pragma unroll
        for (int kx = 0; kx < 5; ++kx) {
            float w = wr[ky * 5 + kx];
            a00 += w * ir[ky][kx];     a01 += w * ir[ky][kx + 1];
            a10 += w * ir[ky + 1][kx]; a11 += w * ir[ky + 1][kx + 1];
        }
    float v = fmaxf(fmaxf(fmaxf(a00, a01), fmaxf(a10, a11)), 0.f);
    ws[WS_SC1 + ((c * 5 + oc) * 32 + py) * 32 + px] = v;
}

// ---------------------------------------------------------------------------
// K1b: conv2 + relu + pool2. 260 blocks = (class, oc); threads 0..195 one
// pooled output each; weights via LDS broadcast, inputs via L1/L2.
// ---------------------------------------------------------------------------
__global__ __launch_bounds__(256) void k_conv2(
    const float* __restrict__ c2w, const float* __restrict__ c2b,
    float* __restrict__ ws)
{
    const int b = blockIdx.x, t = threadIdx.x;
    const int c = b / 10, oc = b - c * 10;

    __shared__ float sw[125];
    if (t < 125) sw[t] = c2w[oc * 125 + t];
    __syncthreads();
    if (t >= 196) return;

    const int py = t / 14, px = t - py * 14;
    const float bias = c2b[oc];
    float a00 = bias, a01 = bias, a10 = bias, a11 = bias;

    const float* base = ws + WS_SC1 + c * 5120 + (2 * py) * 32 + 2 * px;
#pragma unroll
    for (int ic = 0; ic < 5; ++ic) {
        const float* s1 = base + ic * 1024;
        float ir[6][6];
#pragma unroll
        for (int a = 0; a < 6; ++a)
#pragma unroll
            for (int q = 0; q < 3; ++q) {
                float2 v = *(const float2*)&s1[a * 32 + 2 * q];
                ir[a][2 * q] = v.x; ir[a][2 * q + 1] = v.y;
            }
#pragma unroll
        for (int ky = 0; ky < 5; ++ky)
#pragma unroll
            for (int kx = 0; kx < 5; ++kx) {
                float w = sw[ic * 25 + ky * 5 + kx];
                a00 += w * ir[ky][kx];     a01 += w * ir[ky][kx + 1];
                a10 += w * ir[ky + 1][kx]; a11 += w * ir[ky + 1][kx + 1];
            }
    }
    float v = fmaxf(fmaxf(fmaxf(a00, a01), fmaxf(a10, a11)), 0.f);
    ws[WS_FEAT + c * 1960 + oc * 196 + py * 14 + px] = v;
}

// ---------------------------------------------------------------------------
// K2: fc1. 1638 blocks = (class c, j-group of 8); 2 full j-dots per wave.
// ---------------------------------------------------------------------------
__global__ __launch_bounds__(256) void k_fc1(
    const float* __restrict__ fc1w, const float* __restrict__ fc1b,
    float* __restrict__ ws)
{
    const int lane = threadIdx.x & 63, w = threadIdx.x >> 6;
    const int c = blockIdx.x / 63, jg = blockIdx.x - c * 63;
    const int j0 = jg * 8 + 2 * w;
    if (j0 >= 500) return;
    const int j1 = j0 + 1;

    const float* f  = ws + WS_FEAT + c * 1960;
    const float* w0 = fc1w + j0 * 1962;
    const float* w1 = fc1w + j1 * 1962;

    float acc0 = 0.f, acc1 = 0.f;
#pragma unroll
    for (int i = 0; i < 30; ++i) {
        int k = lane + 64 * i;
        float fv = f[k];
        acc0 += w0[k] * fv;
        acc1 += w1[k] * fv;
    }
    {
        int k = lane + 1920;
        if (k < 1960) {
            float fv = f[k];
            acc0 += w0[k] * fv;
            acc1 += w1[k] * fv;
        }
    }
#pragma unroll
    for (int off = 32; off >= 1; off >>= 1) {
        acc0 += __shfl_xor(acc0, off);
        acc1 += __shfl_xor(acc1, off);
    }
    if (lane == 0) {
        ws[WS_FC1P + c * 500 + j0] = acc0 + fc1b[j0];
        ws[WS_FC1P + c * 500 + j1] = acc1 + fc1b[j1];
    }
}

// ---------------------------------------------------------------------------
// K3: fused h + fc2-GEMM + softmax + expert combine.
// 256 blocks x 512 threads, 32 samples/block.
//  Phase 1: h[32][500] -> LDS (stride 501).
//  Phase 2: register tile 2 samples x 4 experts x half-K per thread:
//           8 FMA per k-step vs 2 ds_read_b32 (distinct banks, 4-lane
//           broadcast) + 1 L2-hot global dwordx4 of W2[k][e0..e0+3].
//  Phase 3: wave-per-sample softmax over 64 experts + A-combine.
// ---------------------------------------------------------------------------
__global__ __launch_bounds__(512) void k_logits(
    const float* __restrict__ x, const int* __restrict__ cls,
    const float* __restrict__ fc2b, const float* __restrict__ x_tar,
    const float* __restrict__ ws, float* __restrict__ out)
{
    __shared__ float hs[32 * 501];   // 64.1 KB
    __shared__ float lg[2 * 32 * 64];// 16 KB: [khalf][sample][expert]
    const int t = threadIdx.x;
    const int b0 = blockIdx.x * 32;
    const float* fc1p = ws + WS_FC1P;
    const float* Wx   = ws + WS_WX;
    const float* W2   = ws + WS_W2;
    const float* Af   = ws + WS_AFLAT;

    // ---- Phase 1: h rows into LDS ----
    {
        const int sl = t >> 4;              // 0..31
        const int j0 = t & 15;
        const int b  = b0 + sl;
        const int c  = cls[b];
        const float x0 = x[2 * b], x1 = x[2 * b + 1];
        const float* fr = fc1p + c * 500;
        float* hr = hs + sl * 501;
        for (int j = j0; j < 500; j += 16) {
            float2 wx = *(const float2*)&Wx[2 * j];
            hr[j] = fmaxf(fr[j] + x0 * wx.x + x1 * wx.y, 0.f);
        }
    }
    __syncthreads();

    // ---- Phase 2: GEMM, 2s x 4e x half-K per thread ----
    {
        const int kh = t >> 8;              // 0,1
        const int r  = t & 255;
        const int s0 = (r & 15) * 2;
        const int e0 = (r >> 4) * 4;
        const float* h0p = hs + s0 * 501;
        const float* h1p = h0p + 501;
        float4 a0 = make_float4(0.f, 0.f, 0.f, 0.f);
        float4 a1 = make_float4(0.f, 0.f, 0.f, 0.f);
        const int kbeg = kh * 250, kend = kbeg + 250;
#pragma unroll 5
        for (int k = kbeg; k < kend; ++k) {
            float hv0 = h0p[k], hv1 = h1p[k];
            float4 wv = *(const float4*)&W2[k * 64 + e0];
            a0.x += hv0 * wv.x; a0.y += hv0 * wv.y;
            a0.z += hv0 * wv.z; a0.w += hv0 * wv.w;
            a1.x += hv1 * wv.x; a1.y += hv1 * wv.y;
            a1.z += hv1 * wv.z; a1.w += hv1 * wv.w;
        }
        *(float4*)&lg[(kh * 32 + s0) * 64 + e0]     = a0;
        *(float4*)&lg[(kh * 32 + s0 + 1) * 64 + e0] = a1;
    }
    __syncthreads();

    // ---- Phase 3: softmax + combine; wave w owns samples 4w..4w+3 ----
    {
        const int wv_ = t >> 6;             // 0..7
        const int e   = t & 63;
        const float xt0 = x_tar[0], xt1 = x_tar[1];
        const float be = fc2b[e];
        const float4 a4 = *(const float4*)&Af[4 * e];
#pragma unroll
        for (int i = 0; i < 4; ++i) {
            const int s = wv_ * 4 + i;
            float logit = be + lg[s * 64 + e] + lg[(32 + s) * 64 + e];
            float m = logit;
#pragma unroll
            for (int off = 32; off >= 1; off >>= 1) m = fmaxf(m, __shfl_xor(m, off));
            float ex = __expf(logit - m);
            float sum = ex;
            float m0 = ex * a4.x, m1 = ex * a4.y, m2 = ex * a4.z, m3 = ex * a4.w;
#pragma unroll
            for (int off = 32; off >= 1; off >>= 1) {
                sum += __shfl_xor(sum, off);
                m0 += __shfl_xor(m0, off);
                m1 += __shfl_xor(m1, off);
                m2 += __shfl_xor(m2, off);
                m3 += __shfl_xor(m3, off);
            }
            if (e == 0) {
                const int b = b0 + s;
                float d0 = xt0 - x[2 * b], d1 = xt1 - x[2 * b + 1];
                float inv = 1.f / sum;
                out[2 * b]     = (m0 * d0 + m1 * d1) * inv;
                out[2 * b + 1] = (m2 * d0 + m3 * d1) * inv;
            }
        }
    }
}

extern "C" void kernel_launch(void* const* d_in, const int* in_sizes, int n_in,
                              void* d_out, int out_size, void* d_ws, size_t ws_size,
                              hipStream_t stream) {
    const float* x      = (const float*)d_in[0];
    const int*   cls    = (const int*)  d_in[1];
    const float* images = (const float*)d_in[2];
    const float* c1w    = (const float*)d_in[3];
    const float* c1b    = (const float*)d_in[4];
    const float* c2w    = (const float*)d_in[5];
    const float* c2b    = (const float*)d_in[6];
    const float* fc1w   = (const float*)d_in[7];
    const float* fc1b   = (const float*)d_in[8];
    const float* fc2w   = (const float*)d_in[9];
    const float* fc2b   = (const float*)d_in[10];
    const float* A_B    = (const float*)d_in[11];
    const float* A_C    = (const float*)d_in[12];
    const float* x_tar  = (const float*)d_in[13];
    float* out = (float*)d_out;
    float* ws  = (float*)d_ws;

    k_conv1 <<<522, 256, 0, stream>>>(images, c1w, c1b, fc2w, fc1w, A_B, A_C, ws);
    k_conv2 <<<260, 256, 0, stream>>>(c2w, c2b, ws);
    k_fc1   <<<1638, 256, 0, stream>>>(fc1w, fc1b, ws);
    k_logits<<<256, 512, 0, stream>>>(x, cls, fc2b, x_tar, ws, out);
}

// Round 8
// 145.413 us; speedup vs baseline: 2.1261x; 1.0062x over previous
//
#include <hip/hip_runtime.h>

// Workspace layout (float offsets), ~930 KB of ws used.
#define WS_FEAT   0         // [26][1960]      pooled conv2 (flattened)
#define WS_FC1P   50960     // [26][500]       fc1 class-part + bias
#define WS_W2     63960     // [500][64]       fc2 weights, k-major
#define WS_AFLAT  95960     // [64][4]         A_B + A_C
#define WS_WX     96216     // [500][2]        fc1_w columns 1960,1961

// ---------------------------------------------------------------------------
// K1: fused conv1+conv2 (per-class independence -> no cross-block sync).
// blocks 0..259 = (class c, oc): conv1 (all 5 ch) -> LDS, conv2 for oc.
// conv1 duplicated per oc (10x) — 260 MFLOP extra, cheaper than a dispatch.
// blocks 260,261: prep (W2 k-major pack; Aflat; Wx).
// ---------------------------------------------------------------------------
__global__ __launch_bounds__(256) void k_cnn(
    const float* __restrict__ images,
    const float* __restrict__ c1w, const float* __restrict__ c1b,
    const float* __restrict__ c2w, const float* __restrict__ c2b,
    const float* __restrict__ fc2w, const float* __restrict__ fc1w,
    const float* __restrict__ A_B, const float* __restrict__ A_C,
    float* __restrict__ ws)
{
    const int b = blockIdx.x, t = threadIdx.x;
    if (b >= 260) {
        if (b == 260) {
            float* W2 = ws + WS_W2;
            for (int i = t; i < 32000; i += 256) {   // i = k*64 + e
                int k = i >> 6, e = i & 63;
                W2[i] = fc2w[e * 500 + k];
            }
        } else {
            float* Af = ws + WS_AFLAT;
            if (t < 256) Af[t] = A_B[t] + A_C[t];
            float* Wx = ws + WS_WX;
            for (int i = t; i < 1000; i += 256) {
                int j = i >> 1, k = i & 1;
                Wx[i] = fc1w[j * 1962 + 1960 + k];
            }
        }
        return;
    }

    const int c = b / 10, oc = b - c * 10;

    __shared__ float simg[4624];          // 68x68
    __shared__ float sc1[5 * 32 * 34];    // [5][32][34] stride-34: 8B-aligned f2
    __shared__ float sw1[125];
    __shared__ float sb1[5];
    __shared__ float sw2[125];            // this oc only

    {   // image load, coalesced float2
        const float* im = images + c * 4624;
        for (int i = t; i < 2312; i += 256)
            *(float2*)&simg[2 * i] = *(const float2*)&im[2 * i];
        for (int i = t; i < 125; i += 256) sw1[i] = c1w[i];
        if (t < 5) sb1[t] = c1b[t];
        for (int i = t; i < 125; i += 256) sw2[i] = c2w[oc * 125 + i];
    }
    __syncthreads();

    // conv1 + relu + pool2 -> sc1 [5][32][34]
#pragma unroll
    for (int r = 0; r < 4; ++r) {
        const int pos = t + 256 * r;
        const int py = pos >> 5, px = pos & 31;
        float ir[6][6];
#pragma unroll
        for (int a = 0; a < 6; ++a)
#pragma unroll
            for (int q = 0; q < 3; ++q) {
                float2 v = *(const float2*)&simg[(2 * py + a) * 68 + 2 * px + 2 * q];
                ir[a][2 * q] = v.x; ir[a][2 * q + 1] = v.y;
            }
#pragma unroll
        for (int o = 0; o < 5; ++o) {
            float bias = sb1[o];
            float a00 = bias, a01 = bias, a10 = bias, a11 = bias;
#pragma unroll
            for (int ky = 0; ky < 5; ++ky)
#pragma unroll
                for (int kx = 0; kx < 5; ++kx) {
                    float w = sw1[o * 25 + ky * 5 + kx];
                    a00 += w * ir[ky][kx];     a01 += w * ir[ky][kx + 1];
                    a10 += w * ir[ky + 1][kx]; a11 += w * ir[ky + 1][kx + 1];
                }
            sc1[o * 1088 + py * 34 + px] =
                fmaxf(fmaxf(fmaxf(a00, a01), fmaxf(a10, a11)), 0.f);
        }
    }
    __syncthreads();

    // conv2 + relu + pool2 for this oc -> feat
    if (t < 196) {
        const int py = t / 14, px = t - py * 14;
        const float bias = c2b[oc];
        float a00 = bias, a01 = bias, a10 = bias, a11 = bias;
#pragma unroll
        for (int ic = 0; ic < 5; ++ic) {
            float ir[6][6];
#pragma unroll
            for (int a = 0; a < 6; ++a)
#pragma unroll
                for (int q = 0; q < 3; ++q) {
                    float2 v = *(const float2*)&sc1[ic * 1088 + (2 * py + a) * 34 + 2 * px + 2 * q];
                    ir[a][2 * q] = v.x; ir[a][2 * q + 1] = v.y;
                }
#pragma unroll
            for (int ky = 0; ky < 5; ++ky)
#pragma unroll
                for (int kx = 0; kx < 5; ++kx) {
                    float w = sw2[ic * 25 + ky * 5 + kx];
                    a00 += w * ir[ky][kx];     a01 += w * ir[ky][kx + 1];
                    a10 += w * ir[ky + 1][kx]; a11 += w * ir[ky + 1][kx + 1];
                }
        }
        float v = fmaxf(fmaxf(fmaxf(a00, a01), fmaxf(a10, a11)), 0.f);
        ws[WS_FEAT + c * 1960 + oc * 196 + py * 14 + px] = v;
    }
}

// ---------------------------------------------------------------------------
// K2: fc1. 1638 blocks = (class c, j-group of 8); 2 full j-dots per wave.
// ---------------------------------------------------------------------------
__global__ __launch_bounds__(256) void k_fc1(
    const float* __restrict__ fc1w, const float* __restrict__ fc1b,
    float* __restrict__ ws)
{
    const int lane = threadIdx.x & 63, w = threadIdx.x >> 6;
    const int c = blockIdx.x / 63, jg = blockIdx.x - c * 63;
    const int j0 = jg * 8 + 2 * w;
    if (j0 >= 500) return;
    const int j1 = j0 + 1;

    const float* f  = ws + WS_FEAT + c * 1960;
    const float* w0 = fc1w + j0 * 1962;
    const float* w1 = fc1w + j1 * 1962;

    float acc0 = 0.f, acc1 = 0.f;
#pragma unroll
    for (int i = 0; i < 30; ++i) {
        int k = lane + 64 * i;
        float fv = f[k];
        acc0 += w0[k] * fv;
        acc1 += w1[k] * fv;
    }
    {
        int k = lane + 1920;
        if (k < 1960) {
            float fv = f[k];
            acc0 += w0[k] * fv;
            acc1 += w1[k] * fv;
        }
    }
#pragma unroll
    for (int off = 32; off >= 1; off >>= 1) {
        acc0 += __shfl_xor(acc0, off);
        acc1 += __shfl_xor(acc1, off);
    }
    if (lane == 0) {
        ws[WS_FC1P + c * 500 + j0] = acc0 + fc1b[j0];
        ws[WS_FC1P + c * 500 + j1] = acc1 + fc1b[j1];
    }
}

// ---------------------------------------------------------------------------
// K3: fused h + fc2 GEMM + softmax + combine. 512 blocks x 256 thr,
// 16 samples/block (2 blocks/CU).
//  Phase 1: h[16][508-stride] -> LDS.
//  Phase 2: tile 4s x 4e x k-quarter/thread: per 4k-step 4 ds_read_b128 (h,
//           rows {0,4,8,12}*508 -> disjoint/2-way banks) + 4 coalesced L2
//           float4 (W2) + 64 FMA -> VALU-bound.
//  Phase 3: wave-per-sample softmax + A-combine.
// ---------------------------------------------------------------------------
__global__ __launch_bounds__(256) void k_moe(
    const float* __restrict__ x, const int* __restrict__ cls,
    const float* __restrict__ fc2b, const float* __restrict__ x_tar,
    const float* __restrict__ ws, float* __restrict__ out)
{
    __shared__ float hs[16 * 508];   // 32.5 KB
    __shared__ float lg[4 * 16 * 64];// 16 KB: [kq][sample][expert]
    const int t = threadIdx.x;
    const int b0 = blockIdx.x * 16;
    const float* fc1p = ws + WS_FC1P;
    const float* Wx   = ws + WS_WX;
    const float* W2   = ws + WS_W2;
    const float* Af   = ws + WS_AFLAT;

    // ---- Phase 1: h rows into LDS ----
    {
        const int sl = t >> 4;              // 0..15
        const int j0 = t & 15;
        const int b  = b0 + sl;
        const int c  = cls[b];
        const float x0 = x[2 * b], x1 = x[2 * b + 1];
        const float* fr = fc1p + c * 500;
        float* hr = hs + sl * 508;
        for (int j = j0; j < 500; j += 16) {
            float2 wx = *(const float2*)&Wx[2 * j];
            hr[j] = fmaxf(fr[j] + x0 * wx.x + x1 * wx.y, 0.f);
        }
    }
    __syncthreads();

    // ---- Phase 2: GEMM, 4s x 4e x k-quarter per thread ----
    {
        const int kq = __builtin_amdgcn_readfirstlane(t >> 6);  // wave idx 0..3
        const int rr = t & 63;
        const int e0 = (rr >> 2) * 4;
        const int s0 = (rr & 3) * 4;
        const int kbeg = kq * 128;
        const int kcnt = (kq == 3) ? 116 : 128;   // 500 = 3*128 + 116

        float4 a0 = make_float4(0.f, 0.f, 0.f, 0.f);
        float4 a1 = a0, a2 = a0, a3 = a0;
        const float* h0p = hs + (s0 + 0) * 508;
        const float* h1p = hs + (s0 + 1) * 508;
        const float* h2p = hs + (s0 + 2) * 508;
        const float* h3p = hs + (s0 + 3) * 508;

        for (int k = kbeg; k < kbeg + kcnt; k += 4) {
            float4 w0 = *(const float4*)&W2[(k + 0) * 64 + e0];
            float4 w1 = *(const float4*)&W2[(k + 1) * 64 + e0];
            float4 w2 = *(const float4*)&W2[(k + 2) * 64 + e0];
            float4 w3 = *(const float4*)&W2[(k + 3) * 64 + e0];
            float4 h0 = *(const float4*)&h0p[k];
            float4 h1 = *(const float4*)&h1p[k];
            float4 h2 = *(const float4*)&h2p[k];
            float4 h3 = *(const float4*)&h3p[k];
            a0.x += h0.x*w0.x + h0.y*w1.x + h0.z*w2.x + h0.w*w3.x;
            a0.y += h0.x*w0.y + h0.y*w1.y + h0.z*w2.y + h0.w*w3.y;
            a0.z += h0.x*w0.z + h0.y*w1.z + h0.z*w2.z + h0.w*w3.z;
            a0.w += h0.x*w0.w + h0.y*w1.w + h0.z*w2.w + h0.w*w3.w;
            a1.x += h1.x*w0.x + h1.y*w1.x + h1.z*w2.x + h1.w*w3.x;
            a1.y += h1.x*w0.y + h1.y*w1.y + h1.z*w2.y + h1.w*w3.y;
            a1.z += h1.x*w0.z + h1.y*w1.z + h1.z*w2.z + h1.w*w3.z;
            a1.w += h1.x*w0.w + h1.y*w1.w + h1.z*w2.w + h1.w*w3.w;
            a2.x += h2.x*w0.x + h2.y*w1.x + h2.z*w2.x + h2.w*w3.x;
            a2.y += h2.x*w0.y + h2.y*w1.y + h2.z*w2.y + h2.w*w3.y;
            a2.z += h2.x*w0.z + h2.y*w1.z + h2.z*w2.z + h2.w*w3.z;
            a2.w += h2.x*w0.w + h2.y*w1.w + h2.z*w2.w + h2.w*w3.w;
            a3.x += h3.x*w0.x + h3.y*w1.x + h3.z*w2.x + h3.w*w3.x;
            a3.y += h3.x*w0.y + h3.y*w1.y + h3.z*w2.y + h3.w*w3.y;
            a3.z += h3.x*w0.z + h3.y*w1.z + h3.z*w2.z + h3.w*w3.z;
            a3.w += h3.x*w0.w + h3.y*w1.w + h3.z*w2.w + h3.w*w3.w;
        }
        *(float4*)&lg[(kq * 16 + s0 + 0) * 64 + e0] = a0;
        *(float4*)&lg[(kq * 16 + s0 + 1) * 64 + e0] = a1;
        *(float4*)&lg[(kq * 16 + s0 + 2) * 64 + e0] = a2;
        *(float4*)&lg[(kq * 16 + s0 + 3) * 64 + e0] = a3;
    }
    __syncthreads();

    // ---- Phase 3: softmax + combine; wave w owns samples 4w..4w+3 ----
    {
        const int wv_ = t >> 6;             // 0..3
        const int e   = t & 63;
        const float xt0 = x_tar[0], xt1 = x_tar[1];
        const float be = fc2b[e];
        const float4 a4 = *(const float4*)&Af[4 * e];
#pragma unroll
        for (int i = 0; i < 4; ++i) {
            const int s = wv_ * 4 + i;
            float logit = be + lg[s * 64 + e] + lg[(16 + s) * 64 + e]
                        + lg[(32 + s) * 64 + e] + lg[(48 + s) * 64 + e];
            float m = logit;
#pragma unroll
            for (int off = 32; off >= 1; off >>= 1) m = fmaxf(m, __shfl_xor(m, off));
            float ex = __expf(logit - m);
            float sum = ex;
            float m0 = ex * a4.x, m1 = ex * a4.y, m2 = ex * a4.z, m3 = ex * a4.w;
#pragma unroll
            for (int off = 32; off >= 1; off >>= 1) {
                sum += __shfl_xor(sum, off);
                m0 += __shfl_xor(m0, off);
                m1 += __shfl_xor(m1, off);
                m2 += __shfl_xor(m2, off);
                m3 += __shfl_xor(m3, off);
            }
            if (e == 0) {
                const int b = b0 + s;
                float d0 = xt0 - x[2 * b], d1 = xt1 - x[2 * b + 1];
                float inv = 1.f / sum;
                out[2 * b]     = (m0 * d0 + m1 * d1) * inv;
                out[2 * b + 1] = (m2 * d0 + m3 * d1) * inv;
            }
        }
    }
}

extern "C" void kernel_launch(void* const* d_in, const int* in_sizes, int n_in,
                              void* d_out, int out_size, void* d_ws, size_t ws_size,
                              hipStream_t stream) {
    const float* x      = (const float*)d_in[0];
    const int*   cls    = (const int*)  d_in[1];
    const float* images = (const float*)d_in[2];
    const float* c1w    = (const float*)d_in[3];
    const float* c1b    = (const float*)d_in[4];
    const float* c2w    = (const float*)d_in[5];
    const float* c2b    = (const float*)d_in[6];
    const float* fc1w   = (const float*)d_in[7];
    const float* fc1b   = (const float*)d_in[8];
    const float* fc2w   = (const float*)d_in[9];
    const float* fc2b   = (const float*)d_in[10];
    const float* A_B    = (const float*)d_in[11];
    const float* A_C    = (const float*)d_in[12];
    const float* x_tar  = (const float*)d_in[13];
    float* out = (float*)d_out;
    float* ws  = (float*)d_ws;

    k_cnn<<<262, 256, 0, stream>>>(images, c1w, c1b, c2w, c2b, fc2w, fc1w,
                                   A_B, A_C, ws);
    k_fc1<<<1638, 256, 0, stream>>>(fc1w, fc1b, ws);
    k_moe<<<512, 256, 0, stream>>>(x, cls, fc2b, x_tar, ws, out);
}

// Round 9
// 142.108 us; speedup vs baseline: 2.1756x; 1.0233x over previous
//
#include <hip/hip_runtime.h>

// Workspace layout (float offsets), ~390 KB of ws used.
#define WS_FEAT   0         // [26][1960]      pooled conv2 (flattened)
#define WS_FC1P   50960     // [26][500]       fc1 class-part + bias
#define WS_W2     63960     // [500][64]       fc2 weights, k-major
#define WS_AFLAT  95960     // [64][4]         A_B + A_C
#define WS_WX     96216     // [500][2]        fc1_w columns 1960,1961

// ---------------------------------------------------------------------------
// K1: CNN, occupancy-first. blocks 0..1039 = (class c, oc, quadrant q):
//   load 40x40 image region -> LDS; recompute conv1 (5ch, 18x18 pooled region,
//   12x redundant across blocks = +168M MAC total, ~1 us VALU floor);
//   conv2 ic-parallel: 245 threads x 100-MAC partials -> LDS reduce ->
//   relu -> pool -> feat. 4 blocks/CU hides all latency.
// blocks 1040,1041: prep (W2 k-major pack; Aflat; Wx).
// ---------------------------------------------------------------------------
__global__ __launch_bounds__(256) void k_cnn(
    const float* __restrict__ images,
    const float* __restrict__ c1w, const float* __restrict__ c1b,
    const float* __restrict__ c2w, const float* __restrict__ c2b,
    const float* __restrict__ fc2w, const float* __restrict__ fc1w,
    const float* __restrict__ A_B, const float* __restrict__ A_C,
    float* __restrict__ ws)
{
    const int b = blockIdx.x, t = threadIdx.x;
    if (b >= 1040) {
        if (b == 1040) {
            float* W2 = ws + WS_W2;
            for (int i = t; i < 32000; i += 256) {   // i = k*64 + e
                int k = i >> 6, e = i & 63;
                W2[i] = fc2w[e * 500 + k];
            }
        } else {
            float* Af = ws + WS_AFLAT;
            if (t < 256) Af[t] = A_B[t] + A_C[t];
            float* Wx = ws + WS_WX;
            for (int i = t; i < 1000; i += 256) {
                int j = i >> 1, k = i & 1;
                Wx[i] = fc1w[j * 1962 + 1960 + k];
            }
        }
        return;
    }

    const int c  = b / 40, r = b - c * 40;
    const int oc = r >> 2, q = r & 3;
    const int qy = q >> 1, qx = q & 1;

    __shared__ float simg[1600];     // 40x40 image region
    __shared__ float sc1[1620];      // [5][18][18] pooled conv1 region
    __shared__ float sw1[125];
    __shared__ float sb1[5];
    __shared__ float sw2[125];       // this oc only
    __shared__ float part[980];      // [pos4(196)][ic(5)] conv2 partials

    {   // image region load, origin (28qy, 28qx), coalesced float2
        const float* ib = images + c * 4624 + (28 * qy) * 68 + 28 * qx;
        for (int i = t; i < 800; i += 256) {
            int row = i / 20, col = i - row * 20;
            *(float2*)&simg[row * 40 + 2 * col] = *(const float2*)&ib[row * 68 + 2 * col];
        }
        if (t < 125) { sw1[t] = c1w[t]; sw2[t] = c2w[oc * 125 + t]; }
        if (t < 5) sb1[t] = c1b[t];
    }
    __syncthreads();

    // conv1 + relu + pool2 -> sc1 [5][18][18] (2 rounds of 256 over 324 pos)
    for (int idx = t; idx < 324; idx += 256) {
        int ry = idx / 18, rx = idx - ry * 18;
        float ir[6][6];
#pragma unroll
        for (int a = 0; a < 6; ++a)
#pragma unroll
            for (int q2 = 0; q2 < 3; ++q2) {
                float2 v = *(const float2*)&simg[(2 * ry + a) * 40 + 2 * rx + 2 * q2];
                ir[a][2 * q2] = v.x; ir[a][2 * q2 + 1] = v.y;
            }
#pragma unroll
        for (int o = 0; o < 5; ++o) {
            float bias = sb1[o];
            float a00 = bias, a01 = bias, a10 = bias, a11 = bias;
#pragma unroll
            for (int ky = 0; ky < 5; ++ky)
#pragma unroll
                for (int kx = 0; kx < 5; ++kx) {
                    float w = sw1[o * 25 + ky * 5 + kx];
                    a00 += w * ir[ky][kx];     a01 += w * ir[ky][kx + 1];
                    a10 += w * ir[ky + 1][kx]; a11 += w * ir[ky + 1][kx + 1];
                }
            sc1[o * 324 + idx] =
                fmaxf(fmaxf(fmaxf(a00, a01), fmaxf(a10, a11)), 0.f);
        }
    }
    __syncthreads();

    // conv2 partials: thread = (ic, pooled pos); 4 pre-pool partials each
    if (t < 245) {
        const int ic = t / 49, pos = t - ic * 49;
        const int py = pos / 7, px = pos - py * 7;
        float ir[6][6];
#pragma unroll
        for (int a = 0; a < 6; ++a)
#pragma unroll
            for (int q2 = 0; q2 < 3; ++q2) {
                float2 v = *(const float2*)&sc1[ic * 324 + (2 * py + a) * 18 + 2 * px + 2 * q2];
                ir[a][2 * q2] = v.x; ir[a][2 * q2 + 1] = v.y;
            }
        float p00 = 0.f, p01 = 0.f, p10 = 0.f, p11 = 0.f;
#pragma unroll
        for (int ky = 0; ky < 5; ++ky)
#pragma unroll
            for (int kx = 0; kx < 5; ++kx) {
                float w = sw2[ic * 25 + ky * 5 + kx];
                p00 += w * ir[ky][kx];     p01 += w * ir[ky][kx + 1];
                p10 += w * ir[ky + 1][kx]; p11 += w * ir[ky + 1][kx + 1];
            }
        part[(pos * 4 + 0) * 5 + ic] = p00;
        part[(pos * 4 + 1) * 5 + ic] = p01;
        part[(pos * 4 + 2) * 5 + ic] = p10;
        part[(pos * 4 + 3) * 5 + ic] = p11;
    }
    __syncthreads();

    // reduce over ic (order 0..4, matching reference summation), relu, pool
    if (t < 49) {
        const int py = t / 7, px = t - py * 7;
        const float bias = c2b[oc];
        const float* pp = part + t * 20;
        float s0 = ((((pp[0]  + pp[1])  + pp[2])  + pp[3])  + pp[4])  + bias;
        float s1 = ((((pp[5]  + pp[6])  + pp[7])  + pp[8])  + pp[9])  + bias;
        float s2 = ((((pp[10] + pp[11]) + pp[12]) + pp[13]) + pp[14]) + bias;
        float s3 = ((((pp[15] + pp[16]) + pp[17]) + pp[18]) + pp[19]) + bias;
        float v = fmaxf(fmaxf(fmaxf(s0, s1), fmaxf(s2, s3)), 0.f);
        const int gpy = qy * 7 + py, gpx = qx * 7 + px;
        ws[WS_FEAT + c * 1960 + oc * 196 + gpy * 14 + gpx] = v;
    }
}

// ---------------------------------------------------------------------------
// K2: fc1. 1638 blocks = (class c, j-group of 8); 2 full j-dots per wave.
// ---------------------------------------------------------------------------
__global__ __launch_bounds__(256) void k_fc1(
    const float* __restrict__ fc1w, const float* __restrict__ fc1b,
    float* __restrict__ ws)
{
    const int lane = threadIdx.x & 63, w = threadIdx.x >> 6;
    const int c = blockIdx.x / 63, jg = blockIdx.x - c * 63;
    const int j0 = jg * 8 + 2 * w;
    if (j0 >= 500) return;
    const int j1 = j0 + 1;

    const float* f  = ws + WS_FEAT + c * 1960;
    const float* w0 = fc1w + j0 * 1962;
    const float* w1 = fc1w + j1 * 1962;

    float acc0 = 0.f, acc1 = 0.f;
#pragma unroll
    for (int i = 0; i < 30; ++i) {
        int k = lane + 64 * i;
        float fv = f[k];
        acc0 += w0[k] * fv;
        acc1 += w1[k] * fv;
    }
    {
        int k = lane + 1920;
        if (k < 1960) {
            float fv = f[k];
            acc0 += w0[k] * fv;
            acc1 += w1[k] * fv;
        }
    }
#pragma unroll
    for (int off = 32; off >= 1; off >>= 1) {
        acc0 += __shfl_xor(acc0, off);
        acc1 += __shfl_xor(acc1, off);
    }
    if (lane == 0) {
        ws[WS_FC1P + c * 500 + j0] = acc0 + fc1b[j0];
        ws[WS_FC1P + c * 500 + j1] = acc1 + fc1b[j1];
    }
}

// ---------------------------------------------------------------------------
// K3: fused h + fc2 GEMM + softmax + combine. 512 blocks x 256 thr,
// 16 samples/block (2 blocks/CU). Unchanged from R8 (proven <40 us).
// ---------------------------------------------------------------------------
__global__ __launch_bounds__(256) void k_moe(
    const float* __restrict__ x, const int* __restrict__ cls,
    const float* __restrict__ fc2b, const float* __restrict__ x_tar,
    const float* __restrict__ ws, float* __restrict__ out)
{
    __shared__ float hs[16 * 508];   // 32.5 KB
    __shared__ float lg[4 * 16 * 64];// 16 KB: [kq][sample][expert]
    const int t = threadIdx.x;
    const int b0 = blockIdx.x * 16;
    const float* fc1p = ws + WS_FC1P;
    const float* Wx   = ws + WS_WX;
    const float* W2   = ws + WS_W2;
    const float* Af   = ws + WS_AFLAT;

    // ---- Phase 1: h rows into LDS ----
    {
        const int sl = t >> 4;              // 0..15
        const int j0 = t & 15;
        const int b  = b0 + sl;
        const int c  = cls[b];
        const float x0 = x[2 * b], x1 = x[2 * b + 1];
        const float* fr = fc1p + c * 500;
        float* hr = hs + sl * 508;
        for (int j = j0; j < 500; j += 16) {
            float2 wx = *(const float2*)&Wx[2 * j];
            hr[j] = fmaxf(fr[j] + x0 * wx.x + x1 * wx.y, 0.f);
        }
    }
    __syncthreads();

    // ---- Phase 2: GEMM, 4s x 4e x k-quarter per thread ----
    {
        const int kq = __builtin_amdgcn_readfirstlane(t >> 6);  // wave idx 0..3
        const int rr = t & 63;
        const int e0 = (rr >> 2) * 4;
        const int s0 = (rr & 3) * 4;
        const int kbeg = kq * 128;
        const int kcnt = (kq == 3) ? 116 : 128;   // 500 = 3*128 + 116

        float4 a0 = make_float4(0.f, 0.f, 0.f, 0.f);
        float4 a1 = a0, a2 = a0, a3 = a0;
        const float* h0p = hs + (s0 + 0) * 508;
        const float* h1p = hs + (s0 + 1) * 508;
        const float* h2p = hs + (s0 + 2) * 508;
        const float* h3p = hs + (s0 + 3) * 508;

        for (int k = kbeg; k < kbeg + kcnt; k += 4) {
            float4 w0 = *(const float4*)&W2[(k + 0) * 64 + e0];
            float4 w1 = *(const float4*)&W2[(k + 1) * 64 + e0];
            float4 w2 = *(const float4*)&W2[(k + 2) * 64 + e0];
            float4 w3 = *(const float4*)&W2[(k + 3) * 64 + e0];
            float4 h0 = *(const float4*)&h0p[k];
            float4 h1 = *(const float4*)&h1p[k];
            float4 h2 = *(const float4*)&h2p[k];
            float4 h3 = *(const float4*)&h3p[k];
            a0.x += h0.x*w0.x + h0.y*w1.x + h0.z*w2.x + h0.w*w3.x;
            a0.y += h0.x*w0.y + h0.y*w1.y + h0.z*w2.y + h0.w*w3.y;
            a0.z += h0.x*w0.z + h0.y*w1.z + h0.z*w2.z + h0.w*w3.z;
            a0.w += h0.x*w0.w + h0.y*w1.w + h0.z*w2.w + h0.w*w3.w;
            a1.x += h1.x*w0.x + h1.y*w1.x + h1.z*w2.x + h1.w*w3.x;
            a1.y += h1.x*w0.y + h1.y*w1.y + h1.z*w2.y + h1.w*w3.y;
            a1.z += h1.x*w0.z + h1.y*w1.z + h1.z*w2.z + h1.w*w3.z;
            a1.w += h1.x*w0.w + h1.y*w1.w + h1.z*w2.w + h1.w*w3.w;
            a2.x += h2.x*w0.x + h2.y*w1.x + h2.z*w2.x + h2.w*w3.x;
            a2.y += h2.x*w0.y + h2.y*w1.y + h2.z*w2.y + h2.w*w3.y;
            a2.z += h2.x*w0.z + h2.y*w1.z + h2.z*w2.z + h2.w*w3.z;
            a2.w += h2.x*w0.w + h2.y*w1.w + h2.z*w2.w + h2.w*w3.w;
            a3.x += h3.x*w0.x + h3.y*w1.x + h3.z*w2.x + h3.w*w3.x;
            a3.y += h3.x*w0.y + h3.y*w1.y + h3.z*w2.y + h3.w*w3.y;
            a3.z += h3.x*w0.z + h3.y*w1.z + h3.z*w2.z + h3.w*w3.z;
            a3.w += h3.x*w0.w + h3.y*w1.w + h3.z*w2.w + h3.w*w3.w;
        }
        *(float4*)&lg[(kq * 16 + s0 + 0) * 64 + e0] = a0;
        *(float4*)&lg[(kq * 16 + s0 + 1) * 64 + e0] = a1;
        *(float4*)&lg[(kq * 16 + s0 + 2) * 64 + e0] = a2;
        *(float4*)&lg[(kq * 16 + s0 + 3) * 64 + e0] = a3;
    }
    __syncthreads();

    // ---- Phase 3: softmax + combine; wave w owns samples 4w..4w+3 ----
    {
        const int wv_ = t >> 6;             // 0..3
        const int e   = t & 63;
        const float xt0 = x_tar[0], xt1 = x_tar[1];
        const float be = fc2b[e];
        const float4 a4 = *(const float4*)&Af[4 * e];
#pragma unroll
        for (int i = 0; i < 4; ++i) {
            const int s = wv_ * 4 + i;
            float logit = be + lg[s * 64 + e] + lg[(16 + s) * 64 + e]
                        + lg[(32 + s) * 64 + e] + lg[(48 + s) * 64 + e];
            float m = logit;
#pragma unroll
            for (int off = 32; off >= 1; off >>= 1) m = fmaxf(m, __shfl_xor(m, off));
            float ex = __expf(logit - m);
            float sum = ex;
            float m0 = ex * a4.x, m1 = ex * a4.y, m2 = ex * a4.z, m3 = ex * a4.w;
#pragma unroll
            for (int off = 32; off >= 1; off >>= 1) {
                sum += __shfl_xor(sum, off);
                m0 += __shfl_xor(m0, off);
                m1 += __shfl_xor(m1, off);
                m2 += __shfl_xor(m2, off);
                m3 += __shfl_xor(m3, off);
            }
            if (e == 0) {
                const int b = b0 + s;
                float d0 = xt0 - x[2 * b], d1 = xt1 - x[2 * b + 1];
                float inv = 1.f / sum;
                out[2 * b]     = (m0 * d0 + m1 * d1) * inv;
                out[2 * b + 1] = (m2 * d0 + m3 * d1) * inv;
            }
        }
    }
}

extern "C" void kernel_launch(void* const* d_in, const int* in_sizes, int n_in,
                              void* d_out, int out_size, void* d_ws, size_t ws_size,
                              hipStream_t stream) {
    const float* x      = (const float*)d_in[0];
    const int*   cls    = (const int*)  d_in[1];
    const float* images = (const float*)d_in[2];
    const float* c1w    = (const float*)d_in[3];
    const float* c1b    = (const float*)d_in[4];
    const float* c2w    = (const float*)d_in[5];
    const float* c2b    = (const float*)d_in[6];
    const float* fc1w   = (const float*)d_in[7];
    const float* fc1b   = (const float*)d_in[8];
    const float* fc2w   = (const float*)d_in[9];
    const float* fc2b   = (const float*)d_in[10];
    const float* A_B    = (const float*)d_in[11];
    const float* A_C    = (const float*)d_in[12];
    const float* x_tar  = (const float*)d_in[13];
    float* out = (float*)d_out;
    float* ws  = (float*)d_ws;

    k_cnn<<<1042, 256, 0, stream>>>(images, c1w, c1b, c2w, c2b, fc2w, fc1w,
                                    A_B, A_C, ws);
    k_fc1<<<1638, 256, 0, stream>>>(fc1w, fc1b, ws);
    k_moe<<<512, 256, 0, stream>>>(x, cls, fc2b, x_tar, ws, out);
}